// Round 14
// baseline (151.664 us; speedup 1.0000x reference)
//
#include <hip/hip_runtime.h>

typedef _Float16 h16;
typedef __attribute__((ext_vector_type(4))) _Float16 half4;
typedef __attribute__((ext_vector_type(8))) _Float16 half8;
typedef __attribute__((ext_vector_type(8))) float float8;

#define RANGES 4
#define PPR    64            // chunks per range -> 256 blocks for hist/fill
#define HTHREADS 1024
#define BINS   12800         // nodes per range: 4*12800 = 51200 >= 50000
#define HALF   (BINS / 2)    // packed words per histogram (odeg or ideg)
#define HWORDS (BINS)        // words per partial: HALF odeg + HALF ideg
#define NSEG   100           // 512-node scan segments (51200/512)
#define NFILL  (RANGES * PPR)
#define SMEMB  (BINS * 4 + 512)   // fill cursors + top scan (max phase)

// ======== histogram: 16-bit-packed LDS counters, per-(range,chunk) partials ========
__global__ __launch_bounds__(HTHREADS) void hist_kernel(const int* __restrict__ src,
                                                        const int* __restrict__ dst,
                                                        int* __restrict__ partial, int E) {
  __shared__ int h[HWORDS];  // 51.2 KB
  const int r = blockIdx.x >> 6;   // range 0..3
  const int c = blockIdx.x & 63;   // chunk
  for (int i = threadIdx.x; i < HWORDS; i += HTHREADS) h[i] = 0;
  __syncthreads();
  const int lo = r * BINS;
  const int chunk = (E + PPR - 1) / PPR;
  const int e0 = c * chunk;
  const int e1 = min(E, e0 + chunk);
  for (int e = e0 + threadIdx.x; e < e1; e += HTHREADS) {
    int s = src[e] - lo;
    if ((unsigned)s < (unsigned)BINS) atomicAdd(&h[s >> 1], 1 << ((s & 1) * 16));
    int d = dst[e] - lo;
    if ((unsigned)d < (unsigned)BINS) atomicAdd(&h[HALF + (d >> 1)], 1 << ((d & 1) * 16));
  }
  __syncthreads();
  int* op = partial + (size_t)blockIdx.x * HWORDS;
  for (int i = threadIdx.x; i < HWORDS; i += HTHREADS) op[i] = h[i];
}

// ======== reduce partials -> norms; in-place chunk-prefix; 512-node segment scan ========
__global__ __launch_bounds__(256) void reduce_norm_scan1(
    int* __restrict__ partial, float* __restrict__ nout, float* __restrict__ nin,
    int* __restrict__ rowptr, int* __restrict__ bsums, int N) {
  __shared__ int s[256];
  const int j = blockIdx.x * 256 + threadIdx.x;    // packed word id, < 25600
  const int r = j / HALF;                          // range 0..3
  const int w = j % HALF;
  int* base = partial + (size_t)(r * PPR) * HWORDS;
  int sumO = 0, runI = 0;
#pragma unroll 8
  for (int p = 0; p < PPR; ++p) {
    sumO += base[(size_t)p * HWORDS + w];
    int vI = base[(size_t)p * HWORDS + HALF + w];
    base[(size_t)p * HWORDS + HALF + w] = runI;    // exclusive chunk-prefix (packed; no carry)
    runI += vI;
  }
  const int od0 = sumO & 0xFFFF, od1 = (sumO >> 16) & 0xFFFF;
  const int id0 = runI & 0xFFFF, id1 = (runI >> 16) & 0xFFFF;
  const int n0 = 2 * j, n1 = n0 + 1;
  if (n0 < N) {
    nout[n0] = od0 > 0 ? rsqrtf((float)od0) : 0.f;
    nin[n0]  = id0 > 0 ? rsqrtf((float)id0) : 0.f;
  }
  if (n1 < N) {
    nout[n1] = od1 > 0 ? rsqrtf((float)od1) : 0.f;
    nin[n1]  = id1 > 0 ? rsqrtf((float)id1) : 0.f;
  }
  const int local = id0 + id1;
  int v = local;
  s[threadIdx.x] = v;
  __syncthreads();
#pragma unroll
  for (int off = 1; off < 256; off <<= 1) {
    int tv = 0;
    if (threadIdx.x >= off) tv = s[threadIdx.x - off];
    __syncthreads();
    if (threadIdx.x >= off) s[threadIdx.x] += tv;
    __syncthreads();
  }
  const int excl = s[threadIdx.x] - v;              // segment-local exclusive start
  if (n0 < N) rowptr[n0] = excl;
  if (n1 < N) rowptr[n1] = excl + id0;
  if (threadIdx.x == 255) bsums[blockIdx.x] = s[255];
}

// ======== heterogeneous: blocks [0,256) CSR-fill; blocks [256,..) gemm1 (-> split table) ====
__global__ __launch_bounds__(HTHREADS) void fill_gemm_kernel(
    const int* __restrict__ src, const int* __restrict__ dst,
    const int* __restrict__ rowptr, const int* __restrict__ bsums,
    const int* __restrict__ partial, int* __restrict__ rowptr_abs,
    unsigned short* __restrict__ csr,
    const float* __restrict__ feat, const float* __restrict__ W1,
    const float* __restrict__ nout, half4* __restrict__ tabA,
    int N, int E) {
  __shared__ __align__(16) char smem[SMEMB];
  const int tid = threadIdx.x;

  if (blockIdx.x < NFILL) {
    // ---------------- fill ----------------
    int* cur = (int*)smem;                  // [BINS] absolute cursors (51.2 KB)
    int* top = (int*)(smem + BINS * 4);     // [128] scanned segment sums
    const int r = blockIdx.x & 3;
    const int c = blockIdx.x >> 2;   // chunk 0..63
    if (tid < 128) top[tid] = (tid < NSEG) ? bsums[tid] : 0;
    __syncthreads();
#pragma unroll
    for (int off = 1; off < 128; off <<= 1) {
      int v = 0;
      if (tid < 128 && tid >= off) v = top[tid - off];
      __syncthreads();
      if (tid < 128 && tid >= off) top[tid] += v;
      __syncthreads();
    }
    const int lo = r * BINS;
    const int* pf = partial + (size_t)(r * PPR + c) * HWORDS + HALF;
    for (int n = tid; n < BINS; n += HTHREADS) {
      int g = lo + n;
      int rp = 0;
      if (g < N) {
        int seg = g >> 9;
        rp = rowptr[g] + (seg ? top[seg - 1] : 0);     // absolute row start
        if (c == 0) rowptr_abs[g] = rp;
      }
      int pw = pf[n >> 1];
      cur[n] = rp + ((pw >> ((n & 1) * 16)) & 0xFFFF);
    }
    if (blockIdx.x == 0 && tid == 0) rowptr_abs[N] = E;
    __syncthreads();
    const int chunk = (E + PPR - 1) / PPR;
    const int e0 = c * chunk;
    const int e1 = min(E, e0 + chunk);
    for (int e = e0 + tid; e < e1; e += HTHREADS) {
      int d = dst[e] - lo;
      if ((unsigned)d < (unsigned)BINS) {
        int pos = atomicAdd(&cur[d], 1);
        csr[pos] = (unsigned short)src[e];
      }
    }
  } else {
    // ---------------- gemm1 (128-row tile) -> split fp16 table ----------------
    float* sA = (float*)smem;                   // [128][68]
    float* sB = (float*)(smem + 128 * 68 * 4);  // [64][64]
    const int tile = blockIdx.x - NFILL;
    const int row0 = tile << 7;
    const int ry = tid >> 4;
    const int tx = tid & 15;
    const int r0 = 2 * ry, r1 = r0 + 1;
    float4 acc0 = make_float4(0.f, 0.f, 0.f, 0.f);
    float4 acc1 = make_float4(0.f, 0.f, 0.f, 0.f);
#pragma unroll
    for (int kc = 0; kc < 2; ++kc) {
      __syncthreads();
      for (int i = tid * 4; i < 128 * 64; i += HTHREADS * 4) {
        int rr = i >> 6, cc = i & 63;
        int gr = row0 + rr;
        float4 v = make_float4(0.f, 0.f, 0.f, 0.f);
        if (gr < N) v = *reinterpret_cast<const float4*>(feat + (size_t)gr * 128 + kc * 64 + cc);
        *reinterpret_cast<float4*>(sA + rr * 68 + cc) = v;
      }
      {
        int i = tid * 4;
        int rr = i >> 6, cc = i & 63;
        *reinterpret_cast<float4*>(sB + rr * 64 + cc) =
            *reinterpret_cast<const float4*>(W1 + (size_t)(kc * 64 + rr) * 64 + cc);
      }
      __syncthreads();
#pragma unroll 8
      for (int k = 0; k < 64; ++k) {
        float a0 = sA[r0 * 68 + k], a1 = sA[r1 * 68 + k];
        float4 b = *reinterpret_cast<float4*>(sB + k * 64 + tx * 4);
        acc0.x += a0 * b.x; acc0.y += a0 * b.y; acc0.z += a0 * b.z; acc0.w += a0 * b.w;
        acc1.x += a1 * b.x; acc1.y += a1 * b.y; acc1.z += a1 * b.z; acc1.w += a1 * b.w;
      }
    }
#pragma unroll
    for (int rr = 0; rr < 2; ++rr) {
      const int gr = row0 + (rr ? r1 : r0);
      if (gr >= N) continue;
      float4 v = rr ? acc1 : acc0;
      float no = nout[gr];
      half4 hv;
      hv.x = (h16)(v.x * no); hv.y = (h16)(v.y * no);
      hv.z = (h16)(v.z * no); hv.w = (h16)(v.w * no);
      // split: half = tx>>3, local col-group = tx&7
      tabA[((size_t)(tx >> 3) * N + gr) * 8 + (tx & 7)] = hv;
    }
  }
}

// ======== split gather core: 4 lanes/node cover one 32-feature half, 8-way MLP unroll ====
__device__ __forceinline__ float8 gather32(const int* __restrict__ rowptr,
                                           const unsigned short* __restrict__ csr,
                                           const half8* __restrict__ xv,  // half-table base
                                           int node, int lane) {
  const int b = rowptr[node], e = rowptr[node + 1];
  float8 a0 = 0.f, a1 = 0.f, a2 = 0.f, a3 = 0.f;
  int i = b;
  for (; i + 8 <= e; i += 8) {
    int s0 = csr[i + 0], s1 = csr[i + 1], s2 = csr[i + 2], s3 = csr[i + 3];
    int s4 = csr[i + 4], s5 = csr[i + 5], s6 = csr[i + 6], s7 = csr[i + 7];
    half8 v0 = xv[(size_t)s0 * 4 + lane];
    half8 v1 = xv[(size_t)s1 * 4 + lane];
    half8 v2 = xv[(size_t)s2 * 4 + lane];
    half8 v3 = xv[(size_t)s3 * 4 + lane];
    half8 v4 = xv[(size_t)s4 * 4 + lane];
    half8 v5 = xv[(size_t)s5 * 4 + lane];
    half8 v6 = xv[(size_t)s6 * 4 + lane];
    half8 v7 = xv[(size_t)s7 * 4 + lane];
#pragma unroll
    for (int j = 0; j < 8; ++j) {
      a0[j] += (float)v0[j]; a1[j] += (float)v1[j];
      a2[j] += (float)v2[j]; a3[j] += (float)v3[j];
      a0[j] += (float)v4[j]; a1[j] += (float)v5[j];
      a2[j] += (float)v6[j]; a3[j] += (float)v7[j];
    }
  }
  for (; i + 4 <= e; i += 4) {
    int s0 = csr[i + 0], s1 = csr[i + 1], s2 = csr[i + 2], s3 = csr[i + 3];
    half8 v0 = xv[(size_t)s0 * 4 + lane];
    half8 v1 = xv[(size_t)s1 * 4 + lane];
    half8 v2 = xv[(size_t)s2 * 4 + lane];
    half8 v3 = xv[(size_t)s3 * 4 + lane];
#pragma unroll
    for (int j = 0; j < 8; ++j) {
      a0[j] += (float)v0[j]; a1[j] += (float)v1[j];
      a2[j] += (float)v2[j]; a3[j] += (float)v3[j];
    }
  }
  for (; i < e; ++i) {
    int s = csr[i];
    half8 v = xv[(size_t)s * 4 + lane];
#pragma unroll
    for (int j = 0; j < 8; ++j) a0[j] += (float)v[j];
  }
#pragma unroll
  for (int j = 0; j < 8; ++j) a0[j] = (a0[j] + a1[j]) + (a2[j] + a3[j]);
  return a0;
}

// ======== split aggregation: XCD-partitioned halves ((bid%8)>=4 -> half B) ========
// L1: out = relu(acc*nin + bias_slice); y = fp16(out*nout)   (layer-1)
// !L1: y = fp16(acc*nin)                                     (pre-gemm agg table)
template <bool L1>
__global__ __launch_bounds__(1024) void aggS_kernel(
    const int* __restrict__ rowptr, const unsigned short* __restrict__ csr,
    const half8* __restrict__ xsplit, const float* __restrict__ nin,
    const float* __restrict__ bias, const float* __restrict__ nout,
    half8* __restrict__ ysplit, float* __restrict__ out, int N) {
  const int bid = blockIdx.x, tid = threadIdx.x;
  const int h = (bid & 7) >> 2;                  // 0..3 -> half A ; 4..7 -> half B
  const int c = (bid >> 3) * 4 + (bid & 3);      // chunk within half
  const int node = c * 256 + (tid >> 2);
  if (node >= N) return;
  const int lane = tid & 3;
  const half8* xv = xsplit + (size_t)h * N * 4;
  float8 acc = gather32(rowptr, csr, xv, node, lane);
  const float sN = nin[node];
  if (L1) {
    const float no = nout[node];
    float8 hh;
    half8 hv;
#pragma unroll
    for (int j = 0; j < 8; ++j) {
      hh[j] = fmaxf(acc[j] * sN + bias[h * 32 + lane * 8 + j], 0.f);
      hv[j] = (h16)(hh[j] * no);
    }
    size_t off = (size_t)node * 64 + h * 32 + lane * 8;
    *reinterpret_cast<float4*>(out + off)     = make_float4(hh[0], hh[1], hh[2], hh[3]);
    *reinterpret_cast<float4*>(out + off + 4) = make_float4(hh[4], hh[5], hh[6], hh[7]);
    ysplit[((size_t)h * N + node) * 4 + lane] = hv;
  } else {
    half8 hv;
#pragma unroll
    for (int j = 0; j < 8; ++j) hv[j] = (h16)(acc[j] * sN);
    ysplit[((size_t)h * N + node) * 4 + lane] = hv;
  }
}

// ======== dense gemm over split fp16 agg table: h=relu(A@W+b); out=max; [Csplit=h*nout] ====
template <bool WRITEC>
__global__ __launch_bounds__(512) void gemmS_kernel(
    const half8* __restrict__ A, const float* __restrict__ W,
    const float* __restrict__ bias, const float* __restrict__ nout,
    half4* __restrict__ Cs, float* __restrict__ out, int N) {
  __shared__ float sA[64][68];
  __shared__ float sB[64][64];
  const int t = threadIdx.x;
  const int row0 = blockIdx.x * 64;

  for (int i = t * 4; i < 64 * 64; i += 512 * 4)
    *reinterpret_cast<float4*>(&sB[0][0] + i) = *reinterpret_cast<const float4*>(W + i);

  {
    const int node = t >> 3, l8 = t & 7;
    const int h = l8 >> 2, lane = l8 & 3;
    const int g = row0 + node;
    float8 v = 0.f;
    if (g < N) {
      half8 hv = A[((size_t)h * N + g) * 4 + lane];
#pragma unroll
      for (int j = 0; j < 8; ++j) v[j] = (float)hv[j];
    }
    *reinterpret_cast<float4*>(&sA[node][l8 * 8])     = make_float4(v[0], v[1], v[2], v[3]);
    *reinterpret_cast<float4*>(&sA[node][l8 * 8 + 4]) = make_float4(v[4], v[5], v[6], v[7]);
  }
  __syncthreads();

  const int tx = t & 15;
  const int ry = t >> 4;
  const int r0 = 2 * ry, r1 = r0 + 1;
  float4 a0 = make_float4(0.f, 0.f, 0.f, 0.f);
  float4 a1 = make_float4(0.f, 0.f, 0.f, 0.f);
#pragma unroll 8
  for (int k = 0; k < 64; ++k) {
    float x0 = sA[r0][k], x1 = sA[r1][k];
    float4 b = *reinterpret_cast<float4*>(&sB[k][tx * 4]);
    a0.x += x0 * b.x; a0.y += x0 * b.y; a0.z += x0 * b.z; a0.w += x0 * b.w;
    a1.x += x1 * b.x; a1.y += x1 * b.y; a1.z += x1 * b.z; a1.w += x1 * b.w;
  }

  const float4 bb = *reinterpret_cast<const float4*>(bias + tx * 4);
#pragma unroll
  for (int rr = 0; rr < 2; ++rr) {
    const int gr = row0 + (rr ? r1 : r0);
    if (gr >= N) continue;
    float4 v = rr ? a1 : a0;
    v.x = fmaxf(v.x + bb.x, 0.f);
    v.y = fmaxf(v.y + bb.y, 0.f);
    v.z = fmaxf(v.z + bb.z, 0.f);
    v.w = fmaxf(v.w + bb.w, 0.f);
    size_t off = (size_t)gr * 64 + tx * 4;
    float4 o = *reinterpret_cast<float4*>(out + off);
    o.x = fmaxf(o.x, v.x);
    o.y = fmaxf(o.y, v.y);
    o.z = fmaxf(o.z, v.z);
    o.w = fmaxf(o.w, v.w);
    *reinterpret_cast<float4*>(out + off) = o;
    if (WRITEC) {
      float no = nout[gr];
      half4 hv;
      hv.x = (h16)(v.x * no); hv.y = (h16)(v.y * no);
      hv.z = (h16)(v.z * no); hv.w = (h16)(v.w * no);
      Cs[((size_t)(tx >> 3) * N + gr) * 8 + (tx & 7)] = hv;
    }
  }
}

extern "C" void kernel_launch(void* const* d_in, const int* in_sizes, int n_in,
                              void* d_out, int out_size, void* d_ws, size_t ws_size,
                              hipStream_t stream) {
  const float* feat = (const float*)d_in[0];
  const int* src    = (const int*)d_in[1];
  const int* dst    = (const int*)d_in[2];
  const float* W1   = (const float*)d_in[3];
  const float* b1   = (const float*)d_in[4];
  const float* W2   = (const float*)d_in[5];
  const float* b2   = (const float*)d_in[6];
  const float* W3   = (const float*)d_in[7];
  const float* b3   = (const float*)d_in[8];
  float* out = (float*)d_out;

  const int N = in_sizes[0] / 128;
  const int E = in_sizes[1];

  // ---- workspace layout (no aliasing) ----
  char* p = (char*)d_ws;
  float* nout       = (float*)p;     p += (size_t)N * 4;
  float* nin        = (float*)p;     p += (size_t)N * 4;
  int*   rowptr     = (int*)p;       p += ((size_t)N + 8) * 4;
  int*   rowptr_abs = (int*)p;       p += ((size_t)N + 8) * 4;
  int*   bsums      = (int*)p;       p += 1024 * 4;
  unsigned short* csr = (unsigned short*)p;  p += (((size_t)E + 8) & ~7) * 2;
  p = (char*)(((uintptr_t)p + 15) & ~(uintptr_t)15);
  h16* tabA = (h16*)p;               p += (size_t)N * 64 * 2;   // split table [2][N][32]
  h16* tabB = (h16*)p;               p += (size_t)N * 64 * 2;
  h16* aggT = (h16*)p;               p += (size_t)N * 64 * 2;
  p = (char*)(((uintptr_t)p + 15) & ~(uintptr_t)15);
  int* partial = (int*)p;            p += (size_t)RANGES * PPR * HWORDS * 4;  // 13.1 MB

  const int ngemm = (N + 127) / 128;
  const int chunks = (N + 255) / 256;                 // 256-node chunks per half
  const int aggs_blocks = ((chunks + 3) / 4) * 8;     // XCD-partitioned, both halves
  const int gemms_blocks = (N + 63) / 64;

  // ---- CSR build + layer-1 GEMM (overlapped) ----
  hist_kernel<<<NFILL, HTHREADS, 0, stream>>>(src, dst, partial, E);
  reduce_norm_scan1<<<NSEG, 256, 0, stream>>>(partial, nout, nin, rowptr, bsums, N);
  fill_gemm_kernel<<<NFILL + ngemm, HTHREADS, 0, stream>>>(
      src, dst, rowptr, bsums, partial, rowptr_abs, csr,
      feat, W1, nout, (half4*)tabA, N, E);

  // ---- layer 1: gather tabA -> out=h1; tabB = split fp16(h1*nout) ----
  aggS_kernel<true><<<aggs_blocks, 1024, 0, stream>>>(
      rowptr_abs, csr, (const half8*)tabA, nin, b1, nout, (half8*)tabB, out, N);

  // ---- layer 2: aggT = fp16(gather(tabB)*nin); gemmS -> out=max, tabA = fp16(h2*nout) ----
  aggS_kernel<false><<<aggs_blocks, 1024, 0, stream>>>(
      rowptr_abs, csr, (const half8*)tabB, nin, nullptr, nullptr, (half8*)aggT, nullptr, N);
  gemmS_kernel<true><<<gemms_blocks, 512, 0, stream>>>(
      (const half8*)aggT, W2, b2, nout, (half4*)tabA, out, N);

  // ---- layer 3: aggT = fp16(gather(tabA)*nin); gemmS -> out=max ----
  aggS_kernel<false><<<aggs_blocks, 1024, 0, stream>>>(
      rowptr_abs, csr, (const half8*)tabA, nin, nullptr, nullptr, (half8*)aggT, nullptr, N);
  gemmS_kernel<false><<<gemms_blocks, 512, 0, stream>>>(
      (const half8*)aggT, W3, b3, nullptr, nullptr, out, N);
}

// Round 15
// 147.202 us; speedup vs baseline: 1.0303x; 1.0303x over previous
//
#include <hip/hip_runtime.h>

typedef _Float16 h16;
typedef __attribute__((ext_vector_type(4))) _Float16 half4;
typedef __attribute__((ext_vector_type(8))) _Float16 half8;
typedef __attribute__((ext_vector_type(8))) float float8;

#define RANGES 4
#define PPR    64            // chunks per range -> 256 blocks for hist/fill
#define HTHREADS 1024
#define BINS   12800         // nodes per range: 4*12800 = 51200 >= 50000
#define HALF   (BINS / 2)    // packed words per histogram (odeg or ideg)
#define HWORDS (BINS)        // words per partial: HALF odeg + HALF ideg
#define NSEG   100           // 512-node scan segments (51200/512)
#define NFILL  (RANGES * PPR)
#define SMEMB  (BINS * 4 + 512)   // fill cursors + top scan (max phase)

// ======== histogram: 16-bit-packed LDS counters, per-(range,chunk) partials ========
__global__ __launch_bounds__(HTHREADS) void hist_kernel(const int* __restrict__ src,
                                                        const int* __restrict__ dst,
                                                        int* __restrict__ partial, int E) {
  __shared__ int h[HWORDS];  // 51.2 KB
  const int r = blockIdx.x >> 6;   // range 0..3
  const int c = blockIdx.x & 63;   // chunk
  for (int i = threadIdx.x; i < HWORDS; i += HTHREADS) h[i] = 0;
  __syncthreads();
  const int lo = r * BINS;
  const int chunk = (E + PPR - 1) / PPR;
  const int e0 = c * chunk;
  const int e1 = min(E, e0 + chunk);
  for (int e = e0 + threadIdx.x; e < e1; e += HTHREADS) {
    int s = src[e] - lo;
    if ((unsigned)s < (unsigned)BINS) atomicAdd(&h[s >> 1], 1 << ((s & 1) * 16));
    int d = dst[e] - lo;
    if ((unsigned)d < (unsigned)BINS) atomicAdd(&h[HALF + (d >> 1)], 1 << ((d & 1) * 16));
  }
  __syncthreads();
  int* op = partial + (size_t)blockIdx.x * HWORDS;
  for (int i = threadIdx.x; i < HWORDS; i += HTHREADS) op[i] = h[i];
}

// ======== reduce partials -> norms; in-place chunk-prefix; 512-node segment scan ========
__global__ __launch_bounds__(256) void reduce_norm_scan1(
    int* __restrict__ partial, float* __restrict__ nout, float* __restrict__ nin,
    int* __restrict__ rowptr, int* __restrict__ bsums, int N) {
  __shared__ int s[256];
  const int j = blockIdx.x * 256 + threadIdx.x;    // packed word id, < 25600
  const int r = j / HALF;                          // range 0..3
  const int w = j % HALF;
  int* base = partial + (size_t)(r * PPR) * HWORDS;
  int sumO = 0, runI = 0;
#pragma unroll 8
  for (int p = 0; p < PPR; ++p) {
    sumO += base[(size_t)p * HWORDS + w];
    int vI = base[(size_t)p * HWORDS + HALF + w];
    base[(size_t)p * HWORDS + HALF + w] = runI;    // exclusive chunk-prefix (packed; no carry)
    runI += vI;
  }
  const int od0 = sumO & 0xFFFF, od1 = (sumO >> 16) & 0xFFFF;
  const int id0 = runI & 0xFFFF, id1 = (runI >> 16) & 0xFFFF;
  const int n0 = 2 * j, n1 = n0 + 1;
  if (n0 < N) {
    nout[n0] = od0 > 0 ? rsqrtf((float)od0) : 0.f;
    nin[n0]  = id0 > 0 ? rsqrtf((float)id0) : 0.f;
  }
  if (n1 < N) {
    nout[n1] = od1 > 0 ? rsqrtf((float)od1) : 0.f;
    nin[n1]  = id1 > 0 ? rsqrtf((float)id1) : 0.f;
  }
  const int local = id0 + id1;
  int v = local;
  s[threadIdx.x] = v;
  __syncthreads();
#pragma unroll
  for (int off = 1; off < 256; off <<= 1) {
    int tv = 0;
    if (threadIdx.x >= off) tv = s[threadIdx.x - off];
    __syncthreads();
    if (threadIdx.x >= off) s[threadIdx.x] += tv;
    __syncthreads();
  }
  const int excl = s[threadIdx.x] - v;              // segment-local exclusive start
  if (n0 < N) rowptr[n0] = excl;
  if (n1 < N) rowptr[n1] = excl + id0;
  if (threadIdx.x == 255) bsums[blockIdx.x] = s[255];
}

// ======== heterogeneous: blocks [0,256) CSR-fill; blocks [256,..) gemm1 ========
__global__ __launch_bounds__(HTHREADS) void fill_gemm_kernel(
    const int* __restrict__ src, const int* __restrict__ dst,
    const int* __restrict__ rowptr, const int* __restrict__ bsums,
    const int* __restrict__ partial, int* __restrict__ rowptr_abs,
    unsigned short* __restrict__ csr,
    const float* __restrict__ feat, const float* __restrict__ W1,
    const float* __restrict__ nout, half4* __restrict__ bufAh,
    int N, int E) {
  __shared__ __align__(16) char smem[SMEMB];
  const int tid = threadIdx.x;

  if (blockIdx.x < NFILL) {
    // ---------------- fill ----------------
    int* cur = (int*)smem;                  // [BINS] absolute cursors (51.2 KB)
    int* top = (int*)(smem + BINS * 4);     // [128] scanned segment sums
    const int r = blockIdx.x & 3;
    const int c = blockIdx.x >> 2;   // chunk 0..63
    if (tid < 128) top[tid] = (tid < NSEG) ? bsums[tid] : 0;
    __syncthreads();
#pragma unroll
    for (int off = 1; off < 128; off <<= 1) {
      int v = 0;
      if (tid < 128 && tid >= off) v = top[tid - off];
      __syncthreads();
      if (tid < 128 && tid >= off) top[tid] += v;
      __syncthreads();
    }
    const int lo = r * BINS;
    const int* pf = partial + (size_t)(r * PPR + c) * HWORDS + HALF;
    for (int n = tid; n < BINS; n += HTHREADS) {
      int g = lo + n;
      int rp = 0;
      if (g < N) {
        int seg = g >> 9;
        rp = rowptr[g] + (seg ? top[seg - 1] : 0);     // absolute row start
        if (c == 0) rowptr_abs[g] = rp;
      }
      int pw = pf[n >> 1];
      cur[n] = rp + ((pw >> ((n & 1) * 16)) & 0xFFFF);
    }
    if (blockIdx.x == 0 && tid == 0) rowptr_abs[N] = E;
    __syncthreads();
    const int chunk = (E + PPR - 1) / PPR;
    const int e0 = c * chunk;
    const int e1 = min(E, e0 + chunk);
    for (int e = e0 + tid; e < e1; e += HTHREADS) {
      int d = dst[e] - lo;
      if ((unsigned)d < (unsigned)BINS) {
        int pos = atomicAdd(&cur[d], 1);
        csr[pos] = (unsigned short)src[e];
      }
    }
  } else {
    // ---------------- gemm1 (128-row tile, 1024 threads) ----------------
    float* sA = (float*)smem;                   // [128][68]
    float* sB = (float*)(smem + 128 * 68 * 4);  // [64][64]
    const int tile = blockIdx.x - NFILL;
    const int row0 = tile << 7;
    const int ry = tid >> 4;                // 0..63 -> rows 2ry, 2ry+1
    const int tx = tid & 15;
    const int r0 = 2 * ry, r1 = r0 + 1;
    float4 acc0 = make_float4(0.f, 0.f, 0.f, 0.f);
    float4 acc1 = make_float4(0.f, 0.f, 0.f, 0.f);
#pragma unroll
    for (int kc = 0; kc < 2; ++kc) {
      __syncthreads();
      for (int i = tid * 4; i < 128 * 64; i += HTHREADS * 4) {
        int rr = i >> 6, cc = i & 63;
        int gr = row0 + rr;
        float4 v = make_float4(0.f, 0.f, 0.f, 0.f);
        if (gr < N) v = *reinterpret_cast<const float4*>(feat + (size_t)gr * 128 + kc * 64 + cc);
        *reinterpret_cast<float4*>(sA + rr * 68 + cc) = v;
      }
      {
        int i = tid * 4;
        int rr = i >> 6, cc = i & 63;
        *reinterpret_cast<float4*>(sB + rr * 64 + cc) =
            *reinterpret_cast<const float4*>(W1 + (size_t)(kc * 64 + rr) * 64 + cc);
      }
      __syncthreads();
#pragma unroll 8
      for (int k = 0; k < 64; ++k) {
        float a0 = sA[r0 * 68 + k], a1 = sA[r1 * 68 + k];
        float4 b = *reinterpret_cast<float4*>(sB + k * 64 + tx * 4);
        acc0.x += a0 * b.x; acc0.y += a0 * b.y; acc0.z += a0 * b.z; acc0.w += a0 * b.w;
        acc1.x += a1 * b.x; acc1.y += a1 * b.y; acc1.z += a1 * b.z; acc1.w += a1 * b.w;
      }
    }
#pragma unroll
    for (int rr = 0; rr < 2; ++rr) {
      const int gr = row0 + (rr ? r1 : r0);
      if (gr >= N) continue;
      float4 v = rr ? acc1 : acc0;
      float no = nout[gr];
      half4 hv;
      hv.x = (h16)(v.x * no); hv.y = (h16)(v.y * no);
      hv.z = (h16)(v.z * no); hv.w = (h16)(v.w * no);
      bufAh[(size_t)gr * 16 + tx] = hv;
    }
  }
}

// ======== shared gather core: 8 lanes/node, half8 (16B) loads, 8-way MLP unroll ========
__device__ __forceinline__ float8 gather_row(const int* __restrict__ rowptr,
                                             const unsigned short* __restrict__ csr,
                                             const half8* __restrict__ xv,
                                             int node, int lane) {
  const int b = rowptr[node], e = rowptr[node + 1];
  float8 a0 = 0.f, a1 = 0.f, a2 = 0.f, a3 = 0.f;
  int i = b;
  for (; i + 8 <= e; i += 8) {
    int s0 = csr[i + 0], s1 = csr[i + 1], s2 = csr[i + 2], s3 = csr[i + 3];
    int s4 = csr[i + 4], s5 = csr[i + 5], s6 = csr[i + 6], s7 = csr[i + 7];
    half8 v0 = xv[(size_t)s0 * 8 + lane];
    half8 v1 = xv[(size_t)s1 * 8 + lane];
    half8 v2 = xv[(size_t)s2 * 8 + lane];
    half8 v3 = xv[(size_t)s3 * 8 + lane];
    half8 v4 = xv[(size_t)s4 * 8 + lane];
    half8 v5 = xv[(size_t)s5 * 8 + lane];
    half8 v6 = xv[(size_t)s6 * 8 + lane];
    half8 v7 = xv[(size_t)s7 * 8 + lane];
#pragma unroll
    for (int j = 0; j < 8; ++j) {
      a0[j] += (float)v0[j]; a1[j] += (float)v1[j];
      a2[j] += (float)v2[j]; a3[j] += (float)v3[j];
      a0[j] += (float)v4[j]; a1[j] += (float)v5[j];
      a2[j] += (float)v6[j]; a3[j] += (float)v7[j];
    }
  }
  for (; i + 4 <= e; i += 4) {
    int s0 = csr[i + 0], s1 = csr[i + 1], s2 = csr[i + 2], s3 = csr[i + 3];
    half8 v0 = xv[(size_t)s0 * 8 + lane];
    half8 v1 = xv[(size_t)s1 * 8 + lane];
    half8 v2 = xv[(size_t)s2 * 8 + lane];
    half8 v3 = xv[(size_t)s3 * 8 + lane];
#pragma unroll
    for (int j = 0; j < 8; ++j) {
      a0[j] += (float)v0[j]; a1[j] += (float)v1[j];
      a2[j] += (float)v2[j]; a3[j] += (float)v3[j];
    }
  }
  for (; i < e; ++i) {
    int s = csr[i];
    half8 v = xv[(size_t)s * 8 + lane];
#pragma unroll
    for (int j = 0; j < 8; ++j) a0[j] += (float)v[j];
  }
#pragma unroll
  for (int j = 0; j < 8; ++j) a0[j] = (a0[j] + a1[j]) + (a2[j] + a3[j]);
  return a0;
}

// ======== layer-1 aggregation ========
__global__ __launch_bounds__(512) void agg1_kernel(
    const int* __restrict__ rowptr, const unsigned short* __restrict__ csr,
    const h16* __restrict__ x, const float* __restrict__ nin,
    const float* __restrict__ bias, const float* __restrict__ nout,
    half8* __restrict__ y, float* __restrict__ out, int N) {
  int t = blockIdx.x * 512 + threadIdx.x;
  int node = t >> 3;
  if (node >= N) return;
  int lane = t & 7;
  float8 acc = gather_row(rowptr, csr, reinterpret_cast<const half8*>(x), node, lane);
  const float s = nin[node];
  const float no = nout[node];
  float8 h;
  half8 hv;
#pragma unroll
  for (int j = 0; j < 8; ++j) {
    h[j] = fmaxf(acc[j] * s + bias[lane * 8 + j], 0.f);
    hv[j] = (h16)(h[j] * no);
  }
  size_t off = (size_t)node * 64 + lane * 8;
  *reinterpret_cast<float4*>(out + off)     = make_float4(h[0], h[1], h[2], h[3]);
  *reinterpret_cast<float4*>(out + off + 4) = make_float4(h[4], h[5], h[6], h[7]);
  y[(size_t)node * 8 + lane] = hv;
}

// ======== fused layer (2,3): gather -> nin-scale -> @W -> relu/max/out [, fp16 table] ========
template <bool WRITEC>
__global__ __launch_bounds__(512) void fused_layer(
    const int* __restrict__ rowptr, const unsigned short* __restrict__ csr,
    const h16* __restrict__ x, const float* __restrict__ W,
    const float* __restrict__ nin, const float* __restrict__ bias,
    const float* __restrict__ nout,
    half4* __restrict__ C, float* __restrict__ out, int N) {
  __shared__ float sA[64][68];
  __shared__ float sB[64][64];
  const int t = threadIdx.x;
  const int row0 = blockIdx.x * 64;

  for (int i = t * 4; i < 64 * 64; i += 512 * 4)
    *reinterpret_cast<float4*>(&sB[0][0] + i) = *reinterpret_cast<const float4*>(W + i);

  {
    const int node = t >> 3, lane = t & 7;
    const int g = row0 + node;
    float8 acc = 0.f;
    float s = 0.f;
    if (g < N) {
      acc = gather_row(rowptr, csr, reinterpret_cast<const half8*>(x), g, lane);
      s = nin[g];
    }
    *reinterpret_cast<float4*>(&sA[node][lane * 8]) =
        make_float4(acc[0] * s, acc[1] * s, acc[2] * s, acc[3] * s);
    *reinterpret_cast<float4*>(&sA[node][lane * 8 + 4]) =
        make_float4(acc[4] * s, acc[5] * s, acc[6] * s, acc[7] * s);
  }
  __syncthreads();

  const int tx = t & 15;
  const int ry = t >> 4;
  const int r0 = 2 * ry, r1 = r0 + 1;
  float4 a0 = make_float4(0.f, 0.f, 0.f, 0.f);
  float4 a1 = make_float4(0.f, 0.f, 0.f, 0.f);
#pragma unroll 8
  for (int k = 0; k < 64; ++k) {
    float x0 = sA[r0][k], x1 = sA[r1][k];
    float4 b = *reinterpret_cast<float4*>(&sB[k][tx * 4]);
    a0.x += x0 * b.x; a0.y += x0 * b.y; a0.z += x0 * b.z; a0.w += x0 * b.w;
    a1.x += x1 * b.x; a1.y += x1 * b.y; a1.z += x1 * b.z; a1.w += x1 * b.w;
  }

  const float4 bb = *reinterpret_cast<const float4*>(bias + tx * 4);
#pragma unroll
  for (int rr = 0; rr < 2; ++rr) {
    const int gr = row0 + (rr ? r1 : r0);
    if (gr >= N) continue;
    float4 v = rr ? a1 : a0;
    v.x = fmaxf(v.x + bb.x, 0.f);
    v.y = fmaxf(v.y + bb.y, 0.f);
    v.z = fmaxf(v.z + bb.z, 0.f);
    v.w = fmaxf(v.w + bb.w, 0.f);
    size_t off = (size_t)gr * 64 + tx * 4;
    float4 o = *reinterpret_cast<float4*>(out + off);
    o.x = fmaxf(o.x, v.x);
    o.y = fmaxf(o.y, v.y);
    o.z = fmaxf(o.z, v.z);
    o.w = fmaxf(o.w, v.w);
    *reinterpret_cast<float4*>(out + off) = o;
    if (WRITEC) {
      float no = nout[gr];
      half4 hv;
      hv.x = (h16)(v.x * no); hv.y = (h16)(v.y * no);
      hv.z = (h16)(v.z * no); hv.w = (h16)(v.w * no);
      C[(size_t)gr * 16 + tx] = hv;
    }
  }
}

extern "C" void kernel_launch(void* const* d_in, const int* in_sizes, int n_in,
                              void* d_out, int out_size, void* d_ws, size_t ws_size,
                              hipStream_t stream) {
  const float* feat = (const float*)d_in[0];
  const int* src    = (const int*)d_in[1];
  const int* dst    = (const int*)d_in[2];
  const float* W1   = (const float*)d_in[3];
  const float* b1   = (const float*)d_in[4];
  const float* W2   = (const float*)d_in[5];
  const float* b2   = (const float*)d_in[6];
  const float* W3   = (const float*)d_in[7];
  const float* b3   = (const float*)d_in[8];
  float* out = (float*)d_out;

  const int N = in_sizes[0] / 128;
  const int E = in_sizes[1];

  // ---- workspace layout (no aliasing; ws is ~268 MB) ----
  char* p = (char*)d_ws;
  float* nout       = (float*)p;     p += (size_t)N * 4;
  float* nin        = (float*)p;     p += (size_t)N * 4;
  int*   rowptr     = (int*)p;       p += ((size_t)N + 8) * 4;     // segment-local
  int*   rowptr_abs = (int*)p;       p += ((size_t)N + 8) * 4;     // absolute
  int*   bsums      = (int*)p;       p += 1024 * 4;
  unsigned short* csr = (unsigned short*)p;  p += (((size_t)E + 8) & ~7) * 2;
  p = (char*)(((uintptr_t)p + 15) & ~(uintptr_t)15);
  h16*   bufAh = (h16*)p;            p += (size_t)N * 64 * 2;
  h16*   bufBh = (h16*)p;            p += (size_t)N * 64 * 2;
  p = (char*)(((uintptr_t)p + 15) & ~(uintptr_t)15);
  int*   partial = (int*)p;          p += (size_t)RANGES * PPR * HWORDS * 4;  // 13.1 MB

  const int ngemm = (N + 127) / 128;

  // ---- CSR build + layer-1 GEMM (gemm1 overlapped with fill) ----
  hist_kernel<<<NFILL, HTHREADS, 0, stream>>>(src, dst, partial, E);
  reduce_norm_scan1<<<NSEG, 256, 0, stream>>>(partial, nout, nin, rowptr, bsums, N);
  fill_gemm_kernel<<<NFILL + ngemm, HTHREADS, 0, stream>>>(
      src, dst, rowptr, bsums, partial, rowptr_abs, csr,
      feat, W1, nout, (half4*)bufAh, N, E);

  const int gemm_blocks = (N + 63) / 64;
  const int agg1_blocks = (int)(((size_t)N * 8 + 511) / 512);

  // ---- layer 1 aggregation ----
  agg1_kernel<<<agg1_blocks, 512, 0, stream>>>(rowptr_abs, csr, bufAh, nin, b1, nout,
                                               (half8*)bufBh, out, N);
  // ---- layer 2 ----
  fused_layer<true><<<gemm_blocks, 512, 0, stream>>>(rowptr_abs, csr, bufBh, W2, nin, b2, nout,
                                                     (half4*)bufAh, out, N);
  // ---- layer 3 ----
  fused_layer<false><<<gemm_blocks, 512, 0, stream>>>(rowptr_abs, csr, bufAh, W3, nin, b3, nullptr,
                                                      nullptr, out, N);
}